// Round 1
// baseline (4206.144 us; speedup 1.0000x reference)
//
#include <hip/hip_runtime.h>
#include <math.h>

#define NV 50000
#define ETR 800000
#define EPOS 200000
#define ETEST 400000

// ---------------- degree / dinv ----------------

__global__ void deg_kernel(const int* __restrict__ tei, float* __restrict__ deg) {
    int e = blockIdx.x * blockDim.x + threadIdx.x;
    if (e < ETR) {
        int col = tei[ETR + e];
        atomicAdd(&deg[col], 1.0f);
    }
}

__global__ void dinv_kernel(float* __restrict__ deg_dinv) {
    int i = blockIdx.x * blockDim.x + threadIdx.x;
    if (i < NV) {
        float d = deg_dinv[i] + 2.0f;  // SELF_LOOP_W, always > 0
        deg_dinv[i] = rsqrtf(d);
    }
}

// ---------------- fp32 tiled GEMM: C[M,N] = A[M,K] @ B[K,N] ----------------
// BM=128, BN=128, BK=8, 256 threads, 8x8 micro-tile per thread.
// Requires: N % BN == 0, K % BK == 0 (M guarded).

__global__ __launch_bounds__(256) void sgemm_kernel(
    const float* __restrict__ A, const float* __restrict__ B,
    float* __restrict__ C, int M, int N, int K)
{
    constexpr int BM = 128, BN = 128, BK = 8, TM = 8, TN = 8;
    __shared__ float As[BK][BM];
    __shared__ float Bs[BK][BN];
    int tid = threadIdx.x;
    int tx = tid % (BN / TN);          // 0..15
    int ty = tid / (BN / TN);          // 0..15
    int row0 = blockIdx.y * BM;
    int col0 = blockIdx.x * BN;

    // A tile load mapping: 128x8 floats as float4 along K: 256 threads x 1 float4
    int ar = tid >> 1;                  // 0..127
    int ac = (tid & 1) * 4;             // 0 or 4
    // B tile load mapping: 8x128 floats as float4 along N
    int br = tid >> 5;                  // 0..7
    int bc = (tid & 31) * 4;            // 0..124

    float acc[TM][TN] = {};

    for (int k0 = 0; k0 < K; k0 += BK) {
        float4 av = make_float4(0.f, 0.f, 0.f, 0.f);
        if (row0 + ar < M)
            av = *(const float4*)(&A[(size_t)(row0 + ar) * K + k0 + ac]);
        As[ac + 0][ar] = av.x;
        As[ac + 1][ar] = av.y;
        As[ac + 2][ar] = av.z;
        As[ac + 3][ar] = av.w;
        *(float4*)(&Bs[br][bc]) = *(const float4*)(&B[(size_t)(k0 + br) * N + col0 + bc]);
        __syncthreads();

        #pragma unroll
        for (int kk = 0; kk < BK; ++kk) {
            float a[TM], b[TN];
            #pragma unroll
            for (int i = 0; i < TM; i += 4)
                *(float4*)&a[i] = *(const float4*)&As[kk][ty * TM + i];
            #pragma unroll
            for (int j = 0; j < TN; j += 4)
                *(float4*)&b[j] = *(const float4*)&Bs[kk][tx * TN + j];
            #pragma unroll
            for (int i = 0; i < TM; ++i)
                #pragma unroll
                for (int j = 0; j < TN; ++j)
                    acc[i][j] += a[i] * b[j];
        }
        __syncthreads();
    }

    #pragma unroll
    for (int i = 0; i < TM; ++i) {
        int r = row0 + ty * TM + i;
        if (r < M) {
            #pragma unroll
            for (int j = 0; j < TN; j += 4)
                *(float4*)(&C[(size_t)r * N + col0 + tx * TN + j]) = *(float4*)&acc[i][j];
        }
    }
}

// ---------------- edge scatter: agg[col] += dinv[row]*dinv[col] * h[row] ----------------
// One wave (64 lanes) per edge, V floats per lane (F = 64*V).

template<int F, int V>
__global__ __launch_bounds__(256) void scatter_kernel(
    const int* __restrict__ tei, const float* __restrict__ dinv,
    const float* __restrict__ h, float* __restrict__ agg)
{
    int gid = blockIdx.x * blockDim.x + threadIdx.x;
    int e = gid >> 6;
    int lane = gid & 63;
    if (e >= ETR) return;
    int row = tei[e];
    int col = tei[ETR + e];
    float nrm = dinv[row] * dinv[col];
    const float* hp = h + (size_t)row * F + lane * V;
    float* ap = agg + (size_t)col * F + lane * V;
    if constexpr (V == 4) {
        float4 v = *(const float4*)hp;
        atomicAdd(&ap[0], nrm * v.x);
        atomicAdd(&ap[1], nrm * v.y);
        atomicAdd(&ap[2], nrm * v.z);
        atomicAdd(&ap[3], nrm * v.w);
    } else {
        float2 v = *(const float2*)hp;
        atomicAdd(&ap[0], nrm * v.x);
        atomicAdd(&ap[1], nrm * v.y);
    }
}

// ---------------- finalize: agg = [relu](agg + 2*dinv^2*hlin + bias) ----------------

template<int F, bool RELU>
__global__ __launch_bounds__(256) void finalize_kernel(
    float* __restrict__ agg, const float* __restrict__ hlin,
    const float* __restrict__ dinv, const float* __restrict__ bias)
{
    size_t i = (size_t)blockIdx.x * blockDim.x + threadIdx.x;
    if (i >= (size_t)NV * F) return;
    int node = (int)(i / F);
    int f = (int)(i % F);
    float dv = dinv[node];
    float v = agg[i] + 2.0f * dv * dv * hlin[i] + bias[f];
    if (RELU) v = fmaxf(v, 0.0f);
    agg[i] = v;
}

// ---------------- edge MLP: sigmoid(relu((h[a]+h[b]) @ Wl1 + bl1) @ Wl2 + bl2) ----------------
// One wave per edge. h2 feature dim = 128, hidden = 64 (one output per lane).

__global__ __launch_bounds__(256) void edge_mlp_kernel(
    const int* __restrict__ pos, const int* __restrict__ neg,
    const float* __restrict__ h2, const float* __restrict__ Wl1,
    const float* __restrict__ bl1, const float* __restrict__ Wl2,
    const float* __restrict__ bl2, float* __restrict__ out)
{
    int gid = blockIdx.x * blockDim.x + threadIdx.x;
    int e = gid >> 6;
    int lane = gid & 63;
    if (e >= ETEST) return;
    int a, b;
    if (e < EPOS) {
        a = pos[e];
        b = pos[EPOS + e];
    } else {
        int i = e - EPOS;
        a = neg[i];
        b = neg[EPOS + i];
    }
    const float* ha = h2 + (size_t)a * 128;
    const float* hb = h2 + (size_t)b * 128;
    float e0 = ha[lane] + hb[lane];
    float e1 = ha[64 + lane] + hb[64 + lane];

    float sum = 0.0f;
    #pragma unroll
    for (int k = 0; k < 64; ++k) {
        float ek = __shfl(e0, k);
        sum += ek * Wl1[k * 64 + lane];
    }
    #pragma unroll
    for (int k = 0; k < 64; ++k) {
        float ek = __shfl(e1, k);
        sum += ek * Wl1[(64 + k) * 64 + lane];
    }
    float r = fmaxf(sum + bl1[lane], 0.0f);
    float p = r * Wl2[lane];
    #pragma unroll
    for (int off = 32; off > 0; off >>= 1)
        p += __shfl_xor(p, off);
    if (lane == 0)
        out[e] = 1.0f / (1.0f + expf(-(p + bl2[0])));
}

// ---------------- launch ----------------

extern "C" void kernel_launch(void* const* d_in, const int* in_sizes, int n_in,
                              void* d_out, int out_size, void* d_ws, size_t ws_size,
                              hipStream_t stream) {
    const float* x   = (const float*)d_in[0];
    const int*   tei = (const int*)d_in[1];
    const int*   pos = (const int*)d_in[2];
    const int*   neg = (const int*)d_in[3];
    const float* W1  = (const float*)d_in[4];
    const float* b1  = (const float*)d_in[5];
    const float* W2  = (const float*)d_in[6];
    const float* b2  = (const float*)d_in[7];
    const float* Wl1 = (const float*)d_in[8];
    const float* bl1 = (const float*)d_in[9];
    const float* Wl2 = (const float*)d_in[10];
    const float* bl2 = (const float*)d_in[11];
    float* out = (float*)d_out;

    // workspace layout (floats), with buffer reuse:
    //   dinv  : [50000]
    //   B1    : [12.8M]  h1lin, later h2lin (first 6.4M)
    //   B2    : [12.8M]  agg1/h1, later agg2 (first 6.4M)
    float* ws    = (float*)d_ws;
    float* dinv  = ws;
    float* h1lin = ws + 50176;
    float* agg1  = h1lin + 12800000;
    float* h2lin = h1lin;   // reuse after h1 finalized
    float* agg2  = agg1;    // reuse after gemm2 consumed h1

    hipMemsetAsync(dinv, 0, NV * sizeof(float), stream);
    hipMemsetAsync(agg1, 0, 12800000ull * sizeof(float), stream);

    // degrees + dinv
    deg_kernel<<<(ETR + 255) / 256, 256, 0, stream>>>(tei, dinv);
    dinv_kernel<<<(NV + 255) / 256, 256, 0, stream>>>(dinv);

    // layer 1: h1lin = x @ W1
    sgemm_kernel<<<dim3(256 / 128, (NV + 127) / 128), 256, 0, stream>>>(x, W1, h1lin, NV, 256, 256);
    scatter_kernel<256, 4><<<(ETR * 64) / 256, 256, 0, stream>>>(tei, dinv, h1lin, agg1);
    finalize_kernel<256, true><<<(NV * 256) / 256, 256, 0, stream>>>(agg1, h1lin, dinv, b1);

    // layer 2: h2lin = h1 @ W2   (h1 lives in agg1; h2lin overwrites h1lin)
    sgemm_kernel<<<dim3(128 / 128, (NV + 127) / 128), 256, 0, stream>>>(agg1, W2, h2lin, NV, 128, 256);
    // agg1 (=h1) is dead after gemm2 -> reuse as agg2
    hipMemsetAsync(agg2, 0, 6400000ull * sizeof(float), stream);
    scatter_kernel<128, 2><<<(ETR * 64) / 256, 256, 0, stream>>>(tei, dinv, h2lin, agg2);
    finalize_kernel<128, false><<<(NV * 128) / 256, 256, 0, stream>>>(agg2, h2lin, dinv, b2);

    // edge MLP head
    edge_mlp_kernel<<<(ETEST * 64) / 256, 256, 0, stream>>>(pos, neg, agg2, Wl1, bl1, Wl2, bl2, out);
}

// Round 2
// 1128.467 us; speedup vs baseline: 3.7273x; 3.7273x over previous
//
#include <hip/hip_runtime.h>
#include <math.h>

#define NV 50000
#define ETR 800000
#define EPOS 200000
#define ETEST 400000

// ---------------- CSR build ----------------

__global__ void deg_kernel(const int* __restrict__ tei, int* __restrict__ deg) {
    int e = blockIdx.x * blockDim.x + threadIdx.x;
    if (e < ETR) atomicAdd(&deg[tei[ETR + e]], 1);
}

// Single-block scan over 50k degrees -> ptr (exclusive), cursor copy, dinv.
__global__ __launch_bounds__(1024) void scan_kernel(
    const int* __restrict__ deg, int* __restrict__ ptr,
    int* __restrict__ cursor, float* __restrict__ dinv)
{
    __shared__ int part[1024];
    int t = threadIdx.x;
    constexpr int CH = (NV + 1023) / 1024;  // 49
    int lo = t * CH;
    int hi = min(lo + CH, NV);
    int s = 0;
    for (int i = lo; i < hi; ++i) s += deg[i];
    part[t] = s;
    __syncthreads();
    for (int off = 1; off < 1024; off <<= 1) {
        int v = (t >= off) ? part[t - off] : 0;
        __syncthreads();
        part[t] += v;
        __syncthreads();
    }
    int run = (t > 0) ? part[t - 1] : 0;
    for (int i = lo; i < hi; ++i) {
        int d = deg[i];
        ptr[i] = run;
        cursor[i] = run;
        dinv[i] = rsqrtf((float)d + 2.0f);  // SELF_LOOP_W = 2
        run += d;
    }
    if (t == 1023) ptr[NV] = run;
}

__global__ void fill_kernel(const int* __restrict__ tei, int* __restrict__ cursor,
                            int* __restrict__ csr_row) {
    int e = blockIdx.x * blockDim.x + threadIdx.x;
    if (e < ETR) {
        int row = tei[e];
        int col = tei[ETR + e];
        int p = atomicAdd(&cursor[col], 1);
        csr_row[p] = row;
    }
}

// ---------------- fp32 tiled GEMM: C[M,N] = A[M,K] @ B[K,N] ----------------

__global__ __launch_bounds__(256) void sgemm_kernel(
    const float* __restrict__ A, const float* __restrict__ B,
    float* __restrict__ C, int M, int N, int K)
{
    constexpr int BM = 128, BN = 128, BK = 8, TM = 8, TN = 8;
    __shared__ float As[BK][BM];
    __shared__ float Bs[BK][BN];
    int tid = threadIdx.x;
    int tx = tid % (BN / TN);
    int ty = tid / (BN / TN);
    int row0 = blockIdx.y * BM;
    int col0 = blockIdx.x * BN;

    int ar = tid >> 1;
    int ac = (tid & 1) * 4;
    int br = tid >> 5;
    int bc = (tid & 31) * 4;

    float acc[TM][TN] = {};

    for (int k0 = 0; k0 < K; k0 += BK) {
        float4 av = make_float4(0.f, 0.f, 0.f, 0.f);
        if (row0 + ar < M)
            av = *(const float4*)(&A[(size_t)(row0 + ar) * K + k0 + ac]);
        As[ac + 0][ar] = av.x;
        As[ac + 1][ar] = av.y;
        As[ac + 2][ar] = av.z;
        As[ac + 3][ar] = av.w;
        *(float4*)(&Bs[br][bc]) = *(const float4*)(&B[(size_t)(k0 + br) * N + col0 + bc]);
        __syncthreads();

        #pragma unroll
        for (int kk = 0; kk < BK; ++kk) {
            float a[TM], b[TN];
            #pragma unroll
            for (int i = 0; i < TM; i += 4)
                *(float4*)&a[i] = *(const float4*)&As[kk][ty * TM + i];
            #pragma unroll
            for (int j = 0; j < TN; j += 4)
                *(float4*)&b[j] = *(const float4*)&Bs[kk][tx * TN + j];
            #pragma unroll
            for (int i = 0; i < TM; ++i)
                #pragma unroll
                for (int j = 0; j < TN; ++j)
                    acc[i][j] += a[i] * b[j];
        }
        __syncthreads();
    }

    #pragma unroll
    for (int i = 0; i < TM; ++i) {
        int r = row0 + ty * TM + i;
        if (r < M) {
            #pragma unroll
            for (int j = 0; j < TN; j += 4)
                *(float4*)(&C[(size_t)r * N + col0 + tx * TN + j]) = *(float4*)&acc[i][j];
        }
    }
}

// ---------------- gather: hout[n] = relu?(sum_in + self + bias) ----------------
// One wave per node; V = F/64 floats per lane; no atomics, one write per output.

template<int F, bool RELU>
__global__ __launch_bounds__(256) void gather_kernel(
    const int* __restrict__ ptr, const int* __restrict__ csr_row,
    const float* __restrict__ dinv, const float* __restrict__ hlin,
    const float* __restrict__ bias, float* __restrict__ hout)
{
    int gid = blockIdx.x * blockDim.x + threadIdx.x;
    int node = gid >> 6;
    int lane = gid & 63;
    if (node >= NV) return;
    constexpr int V = F / 64;
    float dc = dinv[node];
    int j0 = ptr[node], j1 = ptr[node + 1];
    float acc[V] = {};

    int j = j0;
    for (; j + 1 < j1; j += 2) {   // 2-way unroll for load ILP
        int r0 = csr_row[j];
        int r1 = csr_row[j + 1];
        float n0 = dinv[r0] * dc;
        float n1 = dinv[r1] * dc;
        const float* p0 = hlin + (size_t)r0 * F + lane * V;
        const float* p1 = hlin + (size_t)r1 * F + lane * V;
        if constexpr (V == 4) {
            float4 v0 = *(const float4*)p0;
            float4 v1 = *(const float4*)p1;
            acc[0] += n0 * v0.x + n1 * v1.x;
            acc[1] += n0 * v0.y + n1 * v1.y;
            acc[2] += n0 * v0.z + n1 * v1.z;
            acc[3] += n0 * v0.w + n1 * v1.w;
        } else {
            float2 v0 = *(const float2*)p0;
            float2 v1 = *(const float2*)p1;
            acc[0] += n0 * v0.x + n1 * v1.x;
            acc[1] += n0 * v0.y + n1 * v1.y;
        }
    }
    if (j < j1) {
        int r0 = csr_row[j];
        float n0 = dinv[r0] * dc;
        const float* p0 = hlin + (size_t)r0 * F + lane * V;
        if constexpr (V == 4) {
            float4 v0 = *(const float4*)p0;
            acc[0] += n0 * v0.x;
            acc[1] += n0 * v0.y;
            acc[2] += n0 * v0.z;
            acc[3] += n0 * v0.w;
        } else {
            float2 v0 = *(const float2*)p0;
            acc[0] += n0 * v0.x;
            acc[1] += n0 * v0.y;
        }
    }

    // self-loop (weight 2, norm dinv^2) + bias (+ relu), single write
    const float* hs = hlin + (size_t)node * F + lane * V;
    float* op = hout + (size_t)node * F + lane * V;
    float sw = 2.0f * dc * dc;
    float o[V];
    #pragma unroll
    for (int k = 0; k < V; ++k) {
        float v = acc[k] + sw * hs[k] + bias[lane * V + k];
        o[k] = RELU ? fmaxf(v, 0.0f) : v;
    }
    if constexpr (V == 4)
        *(float4*)op = make_float4(o[0], o[1], o[2], o[3]);
    else
        *(float2*)op = make_float2(o[0], o[1]);
}

// ---------------- edge MLP ----------------

__global__ __launch_bounds__(256) void edge_mlp_kernel(
    const int* __restrict__ pos, const int* __restrict__ neg,
    const float* __restrict__ h2, const float* __restrict__ Wl1,
    const float* __restrict__ bl1, const float* __restrict__ Wl2,
    const float* __restrict__ bl2, float* __restrict__ out)
{
    int gid = blockIdx.x * blockDim.x + threadIdx.x;
    int e = gid >> 6;
    int lane = gid & 63;
    if (e >= ETEST) return;
    int a, b;
    if (e < EPOS) {
        a = pos[e];
        b = pos[EPOS + e];
    } else {
        int i = e - EPOS;
        a = neg[i];
        b = neg[EPOS + i];
    }
    const float* ha = h2 + (size_t)a * 128;
    const float* hb = h2 + (size_t)b * 128;
    float e0 = ha[lane] + hb[lane];
    float e1 = ha[64 + lane] + hb[64 + lane];

    float sum = 0.0f;
    #pragma unroll
    for (int k = 0; k < 64; ++k) {
        float ek = __shfl(e0, k);
        sum += ek * Wl1[k * 64 + lane];
    }
    #pragma unroll
    for (int k = 0; k < 64; ++k) {
        float ek = __shfl(e1, k);
        sum += ek * Wl1[(64 + k) * 64 + lane];
    }
    float r = fmaxf(sum + bl1[lane], 0.0f);
    float p = r * Wl2[lane];
    #pragma unroll
    for (int off = 32; off > 0; off >>= 1)
        p += __shfl_xor(p, off);
    if (lane == 0)
        out[e] = 1.0f / (1.0f + expf(-(p + bl2[0])));
}

// ---------------- launch ----------------

extern "C" void kernel_launch(void* const* d_in, const int* in_sizes, int n_in,
                              void* d_out, int out_size, void* d_ws, size_t ws_size,
                              hipStream_t stream) {
    const float* x   = (const float*)d_in[0];
    const int*   tei = (const int*)d_in[1];
    const int*   pos = (const int*)d_in[2];
    const int*   neg = (const int*)d_in[3];
    const float* W1  = (const float*)d_in[4];
    const float* b1  = (const float*)d_in[5];
    const float* W2  = (const float*)d_in[6];
    const float* b2  = (const float*)d_in[7];
    const float* Wl1 = (const float*)d_in[8];
    const float* bl1 = (const float*)d_in[9];
    const float* Wl2 = (const float*)d_in[10];
    const float* bl2 = (const float*)d_in[11];
    float* out = (float*)d_out;

    // workspace layout (4B words):
    //   dinv   f32[50000]      @ 0
    //   deg    i32[50000]      @ 50000
    //   ptr    i32[50001]      @ 100000
    //   cursor i32[50000]      @ 150001
    //   csr    i32[800000]     @ 200001
    //   bufA   f32[12.8M]      @ 1000064   (h1lin, then h2lin)
    //   bufB   f32[12.8M]      @ 13800064  (h1, then h2)
    float* fws   = (float*)d_ws;
    int*   iws   = (int*)d_ws;
    float* dinv  = fws;
    int*   deg   = iws + 50000;
    int*   ptr   = iws + 100000;
    int*   cursor= iws + 150001;
    int*   csr   = iws + 200001;
    float* bufA  = fws + 1000064;
    float* bufB  = fws + 13800064;

    hipMemsetAsync(deg, 0, NV * sizeof(int), stream);

    deg_kernel<<<(ETR + 255) / 256, 256, 0, stream>>>(tei, deg);
    scan_kernel<<<1, 1024, 0, stream>>>(deg, ptr, cursor, dinv);
    fill_kernel<<<(ETR + 255) / 256, 256, 0, stream>>>(tei, cursor, csr);

    // layer 1: h1lin = x @ W1 -> bufA; gather -> h1 in bufB (relu fused)
    sgemm_kernel<<<dim3(2, (NV + 127) / 128), 256, 0, stream>>>(x, W1, bufA, NV, 256, 256);
    gather_kernel<256, true><<<(NV * 64 + 255) / 256, 256, 0, stream>>>(ptr, csr, dinv, bufA, b1, bufB);

    // layer 2: h2lin = h1 @ W2 -> bufA (first 6.4M); gather -> h2 in bufB
    sgemm_kernel<<<dim3(1, (NV + 127) / 128), 256, 0, stream>>>(bufB, W2, bufA, NV, 128, 256);
    gather_kernel<128, false><<<(NV * 64 + 255) / 256, 256, 0, stream>>>(ptr, csr, dinv, bufA, b2, bufB);

    // edge MLP head
    edge_mlp_kernel<<<(ETEST * 64 + 255) / 256, 256, 0, stream>>>(pos, neg, bufB, Wl1, bl1, Wl2, bl2, out);
}

// Round 3
// 697.139 us; speedup vs baseline: 6.0334x; 1.6187x over previous
//
#include <hip/hip_runtime.h>
#include <math.h>

#define NV 50000
#define ETR 800000
#define EPOS 200000
#define ETEST 400000

// ---------------- CSR build ----------------

__global__ void deg_kernel(const int* __restrict__ tei, int* __restrict__ deg) {
    int e = blockIdx.x * blockDim.x + threadIdx.x;
    if (e < ETR) atomicAdd(&deg[tei[ETR + e]], 1);
}

// Single-block scan over 50k degrees -> ptr (exclusive), cursor copy, dinv.
__global__ __launch_bounds__(1024) void scan_kernel(
    const int* __restrict__ deg, int* __restrict__ ptr,
    int* __restrict__ cursor, float* __restrict__ dinv)
{
    __shared__ int part[1024];
    int t = threadIdx.x;
    constexpr int CH = (NV + 1023) / 1024;  // 49
    int lo = t * CH;
    int hi = min(lo + CH, NV);
    int s = 0;
    for (int i = lo; i < hi; ++i) s += deg[i];
    part[t] = s;
    __syncthreads();
    for (int off = 1; off < 1024; off <<= 1) {
        int v = (t >= off) ? part[t - off] : 0;
        __syncthreads();
        part[t] += v;
        __syncthreads();
    }
    int run = (t > 0) ? part[t - 1] : 0;
    for (int i = lo; i < hi; ++i) {
        int d = deg[i];
        ptr[i] = run;
        cursor[i] = run;
        dinv[i] = rsqrtf((float)d + 2.0f);  // SELF_LOOP_W = 2
        run += d;
    }
    if (t == 1023) ptr[NV] = run;
}

__global__ void fill_kernel(const int* __restrict__ tei, int* __restrict__ cursor,
                            int* __restrict__ csr_row) {
    int e = blockIdx.x * blockDim.x + threadIdx.x;
    if (e < ETR) {
        int row = tei[e];
        int col = tei[ETR + e];
        int p = atomicAdd(&cursor[col], 1);
        csr_row[p] = row;
    }
}

// ---------------- fp32 tiled GEMM: C[M,N] = A[M,K] @ B[K,N] ----------------

__global__ __launch_bounds__(256) void sgemm_kernel(
    const float* __restrict__ A, const float* __restrict__ B,
    float* __restrict__ C, int M, int N, int K)
{
    constexpr int BM = 128, BN = 128, BK = 8, TM = 8, TN = 8;
    __shared__ float As[BK][BM];
    __shared__ float Bs[BK][BN];
    int tid = threadIdx.x;
    int tx = tid % (BN / TN);
    int ty = tid / (BN / TN);
    int row0 = blockIdx.y * BM;
    int col0 = blockIdx.x * BN;

    int ar = tid >> 1;
    int ac = (tid & 1) * 4;
    int br = tid >> 5;
    int bc = (tid & 31) * 4;

    float acc[TM][TN] = {};

    for (int k0 = 0; k0 < K; k0 += BK) {
        float4 av = make_float4(0.f, 0.f, 0.f, 0.f);
        if (row0 + ar < M)
            av = *(const float4*)(&A[(size_t)(row0 + ar) * K + k0 + ac]);
        As[ac + 0][ar] = av.x;
        As[ac + 1][ar] = av.y;
        As[ac + 2][ar] = av.z;
        As[ac + 3][ar] = av.w;
        *(float4*)(&Bs[br][bc]) = *(const float4*)(&B[(size_t)(k0 + br) * N + col0 + bc]);
        __syncthreads();

        #pragma unroll
        for (int kk = 0; kk < BK; ++kk) {
            float a[TM], b[TN];
            #pragma unroll
            for (int i = 0; i < TM; i += 4)
                *(float4*)&a[i] = *(const float4*)&As[kk][ty * TM + i];
            #pragma unroll
            for (int j = 0; j < TN; j += 4)
                *(float4*)&b[j] = *(const float4*)&Bs[kk][tx * TN + j];
            #pragma unroll
            for (int i = 0; i < TM; ++i)
                #pragma unroll
                for (int j = 0; j < TN; ++j)
                    acc[i][j] += a[i] * b[j];
        }
        __syncthreads();
    }

    #pragma unroll
    for (int i = 0; i < TM; ++i) {
        int r = row0 + ty * TM + i;
        if (r < M) {
            #pragma unroll
            for (int j = 0; j < TN; j += 4)
                *(float4*)(&C[(size_t)r * N + col0 + tx * TN + j]) = *(float4*)&acc[i][j];
        }
    }
}

// ---------------- gather: hout[n] = relu?(sum_in + self + bias) ----------------

template<int F, bool RELU>
__global__ __launch_bounds__(256) void gather_kernel(
    const int* __restrict__ ptr, const int* __restrict__ csr_row,
    const float* __restrict__ dinv, const float* __restrict__ hlin,
    const float* __restrict__ bias, float* __restrict__ hout)
{
    int gid = blockIdx.x * blockDim.x + threadIdx.x;
    int node = gid >> 6;
    int lane = gid & 63;
    if (node >= NV) return;
    constexpr int V = F / 64;
    float dc = dinv[node];
    int j0 = ptr[node], j1 = ptr[node + 1];
    float acc[V] = {};

    int j = j0;
    for (; j + 1 < j1; j += 2) {
        int r0 = csr_row[j];
        int r1 = csr_row[j + 1];
        float n0 = dinv[r0] * dc;
        float n1 = dinv[r1] * dc;
        const float* p0 = hlin + (size_t)r0 * F + lane * V;
        const float* p1 = hlin + (size_t)r1 * F + lane * V;
        if constexpr (V == 4) {
            float4 v0 = *(const float4*)p0;
            float4 v1 = *(const float4*)p1;
            acc[0] += n0 * v0.x + n1 * v1.x;
            acc[1] += n0 * v0.y + n1 * v1.y;
            acc[2] += n0 * v0.z + n1 * v1.z;
            acc[3] += n0 * v0.w + n1 * v1.w;
        } else {
            float2 v0 = *(const float2*)p0;
            float2 v1 = *(const float2*)p1;
            acc[0] += n0 * v0.x + n1 * v1.x;
            acc[1] += n0 * v0.y + n1 * v1.y;
        }
    }
    if (j < j1) {
        int r0 = csr_row[j];
        float n0 = dinv[r0] * dc;
        const float* p0 = hlin + (size_t)r0 * F + lane * V;
        if constexpr (V == 4) {
            float4 v0 = *(const float4*)p0;
            acc[0] += n0 * v0.x;
            acc[1] += n0 * v0.y;
            acc[2] += n0 * v0.z;
            acc[3] += n0 * v0.w;
        } else {
            float2 v0 = *(const float2*)p0;
            acc[0] += n0 * v0.x;
            acc[1] += n0 * v0.y;
        }
    }

    const float* hs = hlin + (size_t)node * F + lane * V;
    float* op = hout + (size_t)node * F + lane * V;
    float sw = 2.0f * dc * dc;
    float o[V];
    #pragma unroll
    for (int k = 0; k < V; ++k) {
        float v = acc[k] + sw * hs[k] + bias[lane * V + k];
        o[k] = RELU ? fmaxf(v, 0.0f) : v;
    }
    if constexpr (V == 4)
        *(float4*)op = make_float4(o[0], o[1], o[2], o[3]);
    else
        *(float2*)op = make_float2(o[0], o[1]);
}

// ---------------- edge MLP as tiled GEMM ----------------
// 64 edges/block, 256 threads. LDS: Wl1s[128][64] (32KB) + EsT[128][64] (32KB).
// Thread (ty,tx) = (tid>>4, tid&15) computes acc[4 edges][4 hidden].
// Then p[i] = sum_j relu(acc+bl1)*Wl2; reduce over tx via padded LDS.

__global__ __launch_bounds__(256) void edge_mlp_tile_kernel(
    const int* __restrict__ pos, const int* __restrict__ neg,
    const float* __restrict__ h2, const float* __restrict__ Wl1,
    const float* __restrict__ bl1, const float* __restrict__ Wl2,
    const float* __restrict__ bl2, float* __restrict__ out)
{
    __shared__ float smem[16384];          // 64 KB exactly
    float* Wl1s = smem;                    // [128][64], row-major k-major
    float* EsT  = smem + 8192;             // [128][64]: EsT[k][e]
    int tid = threadIdx.x;

    // load Wl1 (8192 floats) with 256 threads x 8 float4
    #pragma unroll
    for (int i = 0; i < 8; ++i) {
        int idx = tid * 4 + i * 1024;
        *(float4*)&Wl1s[idx] = *(const float4*)&Wl1[idx];
    }

    // load E tile transposed: thread -> edge et=tid>>2, quarter q=tid&3 (k range q*32..q*32+31)
    int e0 = blockIdx.x * 64;
    int et = tid >> 2, q = tid & 3;
    int eg = e0 + et;
    int a, b;
    if (eg < EPOS) { a = pos[eg]; b = pos[EPOS + eg]; }
    else { int i = eg - EPOS; a = neg[i]; b = neg[EPOS + i]; }
    const float* ha = h2 + (size_t)a * 128 + q * 32;
    const float* hb = h2 + (size_t)b * 128 + q * 32;
    #pragma unroll
    for (int i = 0; i < 32; i += 4) {
        float4 va = *(const float4*)&ha[i];
        float4 vb = *(const float4*)&hb[i];
        int k = q * 32 + i;
        EsT[(k + 0) * 64 + et] = va.x + vb.x;
        EsT[(k + 1) * 64 + et] = va.y + vb.y;
        EsT[(k + 2) * 64 + et] = va.z + vb.z;
        EsT[(k + 3) * 64 + et] = va.w + vb.w;
    }
    __syncthreads();

    int tx = tid & 15;   // hidden group (4 units)
    int ty = tid >> 4;   // edge group (4 edges)
    float acc[4][4] = {};
    #pragma unroll 4
    for (int k = 0; k < 128; ++k) {
        float4 ev = *(float4*)&EsT[k * 64 + ty * 4];     // 4 edges, conflict-free
        float4 w  = *(float4*)&Wl1s[k * 64 + tx * 4];    // 4 hidden, 2-way (free)
        acc[0][0] += ev.x * w.x; acc[0][1] += ev.x * w.y; acc[0][2] += ev.x * w.z; acc[0][3] += ev.x * w.w;
        acc[1][0] += ev.y * w.x; acc[1][1] += ev.y * w.y; acc[1][2] += ev.y * w.z; acc[1][3] += ev.y * w.w;
        acc[2][0] += ev.z * w.x; acc[2][1] += ev.z * w.y; acc[2][2] += ev.z * w.z; acc[2][3] += ev.z * w.w;
        acc[3][0] += ev.w * w.x; acc[3][1] += ev.w * w.y; acc[3][2] += ev.w * w.z; acc[3][3] += ev.w * w.w;
    }

    float4 b1v = *(const float4*)&bl1[tx * 4];
    float4 w2v = *(const float4*)&Wl2[tx * 4];
    float p[4];
    #pragma unroll
    for (int i = 0; i < 4; ++i) {
        p[i]  = fmaxf(acc[i][0] + b1v.x, 0.0f) * w2v.x;
        p[i] += fmaxf(acc[i][1] + b1v.y, 0.0f) * w2v.y;
        p[i] += fmaxf(acc[i][2] + b1v.z, 0.0f) * w2v.z;
        p[i] += fmaxf(acc[i][3] + b1v.w, 0.0f) * w2v.w;
    }

    __syncthreads();
    float* red = EsT;                      // reuse, [64][17] padded
    #pragma unroll
    for (int i = 0; i < 4; ++i)
        red[(ty * 4 + i) * 17 + tx] = p[i];
    __syncthreads();

    if (tid < 64) {
        float s = 0.0f;
        #pragma unroll
        for (int t = 0; t < 16; ++t) s += red[tid * 17 + t];
        out[e0 + tid] = 1.0f / (1.0f + expf(-(s + bl2[0])));
    }
}

// ---------------- launch ----------------

extern "C" void kernel_launch(void* const* d_in, const int* in_sizes, int n_in,
                              void* d_out, int out_size, void* d_ws, size_t ws_size,
                              hipStream_t stream) {
    const float* x   = (const float*)d_in[0];
    const int*   tei = (const int*)d_in[1];
    const int*   pos = (const int*)d_in[2];
    const int*   neg = (const int*)d_in[3];
    const float* W1  = (const float*)d_in[4];
    const float* b1  = (const float*)d_in[5];
    const float* W2  = (const float*)d_in[6];
    const float* b2  = (const float*)d_in[7];
    const float* Wl1 = (const float*)d_in[8];
    const float* bl1 = (const float*)d_in[9];
    const float* Wl2 = (const float*)d_in[10];
    const float* bl2 = (const float*)d_in[11];
    float* out = (float*)d_out;

    float* fws   = (float*)d_ws;
    int*   iws   = (int*)d_ws;
    float* dinv  = fws;
    int*   deg   = iws + 50000;
    int*   ptr   = iws + 100000;
    int*   cursor= iws + 150001;
    int*   csr   = iws + 200001;
    float* bufA  = fws + 1000064;
    float* bufB  = fws + 13800064;

    hipMemsetAsync(deg, 0, NV * sizeof(int), stream);

    deg_kernel<<<(ETR + 255) / 256, 256, 0, stream>>>(tei, deg);
    scan_kernel<<<1, 1024, 0, stream>>>(deg, ptr, cursor, dinv);
    fill_kernel<<<(ETR + 255) / 256, 256, 0, stream>>>(tei, cursor, csr);

    // layer 1: h1lin = x @ W1 -> bufA; gather -> h1 in bufB (relu fused)
    sgemm_kernel<<<dim3(2, (NV + 127) / 128), 256, 0, stream>>>(x, W1, bufA, NV, 256, 256);
    gather_kernel<256, true><<<(NV * 64 + 255) / 256, 256, 0, stream>>>(ptr, csr, dinv, bufA, b1, bufB);

    // layer 2: h2lin = h1 @ W2 -> bufA; gather -> h2 in bufB
    sgemm_kernel<<<dim3(1, (NV + 127) / 128), 256, 0, stream>>>(bufB, W2, bufA, NV, 128, 256);
    gather_kernel<128, false><<<(NV * 64 + 255) / 256, 256, 0, stream>>>(ptr, csr, dinv, bufA, b2, bufB);

    // edge MLP head (tiled GEMM form)
    edge_mlp_tile_kernel<<<ETEST / 64, 256, 0, stream>>>(pos, neg, bufB, Wl1, bl1, Wl2, bl2, out);
}

// Round 4
// 399.856 us; speedup vs baseline: 10.5191x; 1.7435x over previous
//
#include <hip/hip_runtime.h>
#include <math.h>

#define NV 50000
#define ETR 800000
#define EPOS 200000
#define ETEST 400000

typedef __attribute__((ext_vector_type(8))) short bf16x8;
typedef __attribute__((ext_vector_type(8))) unsigned short ushortx8;
typedef __attribute__((ext_vector_type(4))) float f32x4;

__device__ inline unsigned short f2b(float f) {
    union { float f; unsigned u; } v; v.f = f;
    unsigned r = v.u + 0x7fffu + ((v.u >> 16) & 1u);   // RNE
    return (unsigned short)(r >> 16);
}
__device__ inline float blo(unsigned q) { union { unsigned u; float f; } v; v.u = q << 16; return v.f; }
__device__ inline float bhi(unsigned q) { union { unsigned u; float f; } v; v.u = q & 0xffff0000u; return v.f; }

// ---------------- CSR build ----------------

__global__ void deg_kernel(const int* __restrict__ tei, int* __restrict__ deg) {
    int e = blockIdx.x * blockDim.x + threadIdx.x;
    if (e < ETR) atomicAdd(&deg[tei[ETR + e]], 1);
}

__global__ __launch_bounds__(1024) void partial_kernel(const int* __restrict__ deg,
                                                       int* __restrict__ partials) {
    int i = blockIdx.x * 1024 + threadIdx.x;
    int v = (i < NV) ? deg[i] : 0;
    #pragma unroll
    for (int off = 32; off > 0; off >>= 1) v += __shfl_xor(v, off);
    __shared__ int wsum[16];
    if ((threadIdx.x & 63) == 0) wsum[threadIdx.x >> 6] = v;
    __syncthreads();
    if (threadIdx.x == 0) {
        int s = 0;
        #pragma unroll
        for (int k = 0; k < 16; ++k) s += wsum[k];
        partials[blockIdx.x] = s;
    }
}

__global__ __launch_bounds__(1024) void ptr_kernel(
    const int* __restrict__ deg, const int* __restrict__ partials,
    int* __restrict__ ptr, int* __restrict__ cursor, float* __restrict__ dinv)
{
    int b = blockIdx.x, t = threadIdx.x;
    int i = b * 1024 + t;
    int d = (i < NV) ? deg[i] : 0;
    int lane = t & 63, w = t >> 6;
    int v = d;
    #pragma unroll
    for (int off = 1; off < 64; off <<= 1) {
        int u = __shfl_up(v, off);
        if (lane >= off) v += u;
    }
    __shared__ int wsum[16], woff[16];
    if (lane == 63) wsum[w] = v;
    __syncthreads();
    if (t == 0) {
        int s = 0;
        for (int k = 0; k < b; ++k) s += partials[k];
        for (int k = 0; k < 16; ++k) { woff[k] = s; s += wsum[k]; }
    }
    __syncthreads();
    int excl = woff[w] + v - d;
    if (i < NV) {
        ptr[i] = excl;
        cursor[i] = excl;
        dinv[i] = rsqrtf((float)d + 2.0f);   // SELF_LOOP_W = 2
        if (i == NV - 1) ptr[NV] = excl + d;
    }
}

__global__ void fill_kernel(const int* __restrict__ tei, int* __restrict__ cursor,
                            int* __restrict__ csr_row) {
    int e = blockIdx.x * blockDim.x + threadIdx.x;
    if (e < ETR) {
        int row = tei[e];
        int col = tei[ETR + e];
        int p = atomicAdd(&cursor[col], 1);
        csr_row[p] = row;
    }
}

// ---------------- converts ----------------

__global__ void cvt_x_kernel(const float* __restrict__ x, unsigned short* __restrict__ xb, int n4) {
    int i = blockIdx.x * blockDim.x + threadIdx.x;
    if (i < n4) {
        float4 v = *(const float4*)&x[i * 4];
        union { unsigned short u[4]; uint2 q; } o;
        o.u[0] = f2b(v.x); o.u[1] = f2b(v.y); o.u[2] = f2b(v.z); o.u[3] = f2b(v.w);
        *(uint2*)&xb[i * 4] = o.q;
    }
}

// Wt[n][k] = bf16(W[k][n])
__global__ void cvt_wt_kernel(const float* __restrict__ W, unsigned short* __restrict__ Wt,
                              int K, int N) {
    int idx = blockIdx.x * blockDim.x + threadIdx.x;
    if (idx < N * K) {
        int n = idx / K, k = idx - n * K;
        Wt[idx] = f2b(W[k * N + n]);
    }
}

// ---------------- bf16 MFMA GEMM: C[M][N] = A[M][K] @ Bt[N][K]^T ----------------
// 128x128 tile, 4 waves in 2x2, BK=64, 16x16x32 MFMA, XOR-swizzled LDS (T2).

template<int N, int K, bool OUTBF>
__global__ __launch_bounds__(256) void mfma_gemm_kernel(
    const unsigned short* __restrict__ A, const unsigned short* __restrict__ Bt,
    void* __restrict__ Cv, int M)
{
    constexpr int BK = 64;
    __shared__ unsigned short Asm[128][BK];
    __shared__ unsigned short Bsm[128][BK];
    int tid = threadIdx.x;
    int lane = tid & 63, wid = tid >> 6;
    int wr = wid >> 1, wc = wid & 1;
    int row0 = blockIdx.x * 128, col0 = blockIdx.y * 128;

    int sr = tid >> 3;                 // staging row 0..31 within group
    int s8 = tid & 7;                  // 16B slot
    int sswz = s8 ^ (sr & 7);          // swizzled slot (rows advance by 32 -> sr&7 invariant)
    int fr = lane & 15;
    int g  = lane >> 4;

    f32x4 acc[4][4] = {};

    for (int k0 = 0; k0 < K; k0 += BK) {
        #pragma unroll
        for (int i = 0; i < 4; ++i) {
            int r = sr + i * 32;
            int gr = row0 + r;
            ushortx8 va = {0, 0, 0, 0, 0, 0, 0, 0};
            if (gr < M) va = *(const ushortx8*)&A[(size_t)gr * K + k0 + s8 * 8];
            *(ushortx8*)&Asm[r][sswz * 8] = va;
            ushortx8 vb = *(const ushortx8*)&Bt[(size_t)(col0 + r) * K + k0 + s8 * 8];
            *(ushortx8*)&Bsm[r][sswz * 8] = vb;
        }
        __syncthreads();
        #pragma unroll
        for (int kf = 0; kf < BK; kf += 32) {
            int sbase = kf >> 3;       // 0 or 4
            bf16x8 af[4], bfr[4];
            #pragma unroll
            for (int m = 0; m < 4; ++m) {
                int rr = wr * 64 + m * 16 + fr;
                af[m] = *(const bf16x8*)&Asm[rr][((sbase + g) ^ (fr & 7)) * 8];
            }
            #pragma unroll
            for (int n = 0; n < 4; ++n) {
                int rr = wc * 64 + n * 16 + fr;
                bfr[n] = *(const bf16x8*)&Bsm[rr][((sbase + g) ^ (fr & 7)) * 8];
            }
            #pragma unroll
            for (int m = 0; m < 4; ++m)
                #pragma unroll
                for (int n = 0; n < 4; ++n)
                    acc[m][n] = __builtin_amdgcn_mfma_f32_16x16x32_bf16(af[m], bfr[n], acc[m][n], 0, 0, 0);
        }
        __syncthreads();
    }

    // C/D layout: col = lane&15, row = (lane>>4)*4 + j  (verified m89/m91)
    #pragma unroll
    for (int m = 0; m < 4; ++m) {
        int rbase = row0 + wr * 64 + m * 16 + g * 4;
        #pragma unroll
        for (int j = 0; j < 4; ++j) {
            int r = rbase + j;
            if (r < M) {
                #pragma unroll
                for (int n = 0; n < 4; ++n) {
                    int c = col0 + wc * 64 + n * 16 + fr;
                    float v = acc[m][n][j];
                    if constexpr (OUTBF)
                        ((unsigned short*)Cv)[(size_t)r * N + c] = f2b(v);
                    else
                        ((float*)Cv)[(size_t)r * N + c] = v;
                }
            }
        }
    }
}

// ---------------- gather (bf16 in): hout[n] = relu?(sum_in + self + bias) ----------------

template<int F, bool RELU, bool OUTBF>
__global__ __launch_bounds__(256) void gather_kernel(
    const int* __restrict__ ptr, const int* __restrict__ csr,
    const float* __restrict__ dinv, const unsigned short* __restrict__ hlin,
    const float* __restrict__ bias, void* __restrict__ hout)
{
    constexpr int V = F / 64;
    int gid = blockIdx.x * blockDim.x + threadIdx.x;
    int node = gid >> 6, lane = gid & 63;
    if (node >= NV) return;
    float dc = dinv[node];
    int j0 = ptr[node], j1 = ptr[node + 1];
    float acc[V] = {};
    const unsigned short* hb = hlin + lane * V;

    int j = j0;
    for (; j + 1 < j1; j += 2) {
        int r0 = csr[j], r1 = csr[j + 1];
        float n0 = dinv[r0] * dc, n1 = dinv[r1] * dc;
        const unsigned short* p0 = hb + (size_t)r0 * F;
        const unsigned short* p1 = hb + (size_t)r1 * F;
        if constexpr (V == 4) {
            uint2 q0 = *(const uint2*)p0;
            uint2 q1 = *(const uint2*)p1;
            acc[0] += n0 * blo(q0.x) + n1 * blo(q1.x);
            acc[1] += n0 * bhi(q0.x) + n1 * bhi(q1.x);
            acc[2] += n0 * blo(q0.y) + n1 * blo(q1.y);
            acc[3] += n0 * bhi(q0.y) + n1 * bhi(q1.y);
        } else {
            unsigned q0 = *(const unsigned*)p0;
            unsigned q1 = *(const unsigned*)p1;
            acc[0] += n0 * blo(q0) + n1 * blo(q1);
            acc[1] += n0 * bhi(q0) + n1 * bhi(q1);
        }
    }
    if (j < j1) {
        int r0 = csr[j];
        float n0 = dinv[r0] * dc;
        const unsigned short* p0 = hb + (size_t)r0 * F;
        if constexpr (V == 4) {
            uint2 q0 = *(const uint2*)p0;
            acc[0] += n0 * blo(q0.x);
            acc[1] += n0 * bhi(q0.x);
            acc[2] += n0 * blo(q0.y);
            acc[3] += n0 * bhi(q0.y);
        } else {
            unsigned q0 = *(const unsigned*)p0;
            acc[0] += n0 * blo(q0);
            acc[1] += n0 * bhi(q0);
        }
    }

    // self-loop (weight 2, norm dc^2) + bias (+relu)
    const unsigned short* ps = hb + (size_t)node * F;
    float sw = 2.0f * dc * dc;
    float o[V];
    if constexpr (V == 4) {
        uint2 qs = *(const uint2*)ps;
        o[0] = acc[0] + sw * blo(qs.x) + bias[lane * 4 + 0];
        o[1] = acc[1] + sw * bhi(qs.x) + bias[lane * 4 + 1];
        o[2] = acc[2] + sw * blo(qs.y) + bias[lane * 4 + 2];
        o[3] = acc[3] + sw * bhi(qs.y) + bias[lane * 4 + 3];
    } else {
        unsigned qs = *(const unsigned*)ps;
        o[0] = acc[0] + sw * blo(qs) + bias[lane * 2 + 0];
        o[1] = acc[1] + sw * bhi(qs) + bias[lane * 2 + 1];
    }
    #pragma unroll
    for (int k = 0; k < V; ++k)
        if (RELU) o[k] = fmaxf(o[k], 0.0f);

    if constexpr (OUTBF) {
        unsigned short* op = (unsigned short*)hout + (size_t)node * F + lane * V;
        if constexpr (V == 4) {
            union { unsigned short u[4]; uint2 q; } pk;
            pk.u[0] = f2b(o[0]); pk.u[1] = f2b(o[1]); pk.u[2] = f2b(o[2]); pk.u[3] = f2b(o[3]);
            *(uint2*)op = pk.q;
        } else {
            union { unsigned short u[2]; unsigned q; } pk;
            pk.u[0] = f2b(o[0]); pk.u[1] = f2b(o[1]);
            *(unsigned*)op = pk.q;
        }
    } else {
        float* op = (float*)hout + (size_t)node * F + lane * V;
        if constexpr (V == 4)
            *(float4*)op = make_float4(o[0], o[1], o[2], o[3]);
        else
            *(float2*)op = make_float2(o[0], o[1]);
    }
}

// ---------------- edge MLP as tiled GEMM (f32) ----------------

__global__ __launch_bounds__(256) void edge_mlp_tile_kernel(
    const int* __restrict__ pos, const int* __restrict__ neg,
    const float* __restrict__ h2, const float* __restrict__ Wl1,
    const float* __restrict__ bl1, const float* __restrict__ Wl2,
    const float* __restrict__ bl2, float* __restrict__ out)
{
    __shared__ float smem[16384];
    float* Wl1s = smem;                    // [128][64]
    float* EsT  = smem + 8192;             // [128][64]: EsT[k][e]
    int tid = threadIdx.x;

    #pragma unroll
    for (int i = 0; i < 8; ++i) {
        int idx = tid * 4 + i * 1024;
        *(float4*)&Wl1s[idx] = *(const float4*)&Wl1[idx];
    }

    int e0 = blockIdx.x * 64;
    int et = tid >> 2, q = tid & 3;
    int eg = e0 + et;
    int a, b;
    if (eg < EPOS) { a = pos[eg]; b = pos[EPOS + eg]; }
    else { int i = eg - EPOS; a = neg[i]; b = neg[EPOS + i]; }
    const float* ha = h2 + (size_t)a * 128 + q * 32;
    const float* hb = h2 + (size_t)b * 128 + q * 32;
    #pragma unroll
    for (int i = 0; i < 32; i += 4) {
        float4 va = *(const float4*)&ha[i];
        float4 vb = *(const float4*)&hb[i];
        int k = q * 32 + i;
        EsT[(k + 0) * 64 + et] = va.x + vb.x;
        EsT[(k + 1) * 64 + et] = va.y + vb.y;
        EsT[(k + 2) * 64 + et] = va.z + vb.z;
        EsT[(k + 3) * 64 + et] = va.w + vb.w;
    }
    __syncthreads();

    int tx = tid & 15;
    int ty = tid >> 4;
    float acc[4][4] = {};
    #pragma unroll 4
    for (int k = 0; k < 128; ++k) {
        float4 ev = *(float4*)&EsT[k * 64 + ty * 4];
        float4 w  = *(float4*)&Wl1s[k * 64 + tx * 4];
        acc[0][0] += ev.x * w.x; acc[0][1] += ev.x * w.y; acc[0][2] += ev.x * w.z; acc[0][3] += ev.x * w.w;
        acc[1][0] += ev.y * w.x; acc[1][1] += ev.y * w.y; acc[1][2] += ev.y * w.z; acc[1][3] += ev.y * w.w;
        acc[2][0] += ev.z * w.x; acc[2][1] += ev.z * w.y; acc[2][2] += ev.z * w.z; acc[2][3] += ev.z * w.w;
        acc[3][0] += ev.w * w.x; acc[3][1] += ev.w * w.y; acc[3][2] += ev.w * w.z; acc[3][3] += ev.w * w.w;
    }

    float4 b1v = *(const float4*)&bl1[tx * 4];
    float4 w2v = *(const float4*)&Wl2[tx * 4];
    float p[4];
    #pragma unroll
    for (int i = 0; i < 4; ++i) {
        p[i]  = fmaxf(acc[i][0] + b1v.x, 0.0f) * w2v.x;
        p[i] += fmaxf(acc[i][1] + b1v.y, 0.0f) * w2v.y;
        p[i] += fmaxf(acc[i][2] + b1v.z, 0.0f) * w2v.z;
        p[i] += fmaxf(acc[i][3] + b1v.w, 0.0f) * w2v.w;
    }

    __syncthreads();
    float* red = EsT;
    #pragma unroll
    for (int i = 0; i < 4; ++i)
        red[(ty * 4 + i) * 17 + tx] = p[i];
    __syncthreads();

    if (tid < 64) {
        float s = 0.0f;
        #pragma unroll
        for (int t = 0; t < 16; ++t) s += red[tid * 17 + t];
        out[e0 + tid] = 1.0f / (1.0f + expf(-(s + bl2[0])));
    }
}

// ---------------- launch ----------------

extern "C" void kernel_launch(void* const* d_in, const int* in_sizes, int n_in,
                              void* d_out, int out_size, void* d_ws, size_t ws_size,
                              hipStream_t stream) {
    const float* x   = (const float*)d_in[0];
    const int*   tei = (const int*)d_in[1];
    const int*   pos = (const int*)d_in[2];
    const int*   neg = (const int*)d_in[3];
    const float* W1  = (const float*)d_in[4];
    const float* b1  = (const float*)d_in[5];
    const float* W2  = (const float*)d_in[6];
    const float* b2  = (const float*)d_in[7];
    const float* Wl1 = (const float*)d_in[8];
    const float* bl1 = (const float*)d_in[9];
    const float* Wl2 = (const float*)d_in[10];
    const float* bl2 = (const float*)d_in[11];
    float* out = (float*)d_out;

    // workspace (word offsets, total ~81MB):
    float* fws = (float*)d_ws;
    int*   iws = (int*)d_ws;
    unsigned short* usws = (unsigned short*)d_ws;
    float* dinv     = fws;                       // [50000]
    int*   deg      = iws + 50000;               // [50000]
    int*   ptr      = iws + 100000;              // [50001]
    int*   cursor   = iws + 150001;              // [50000]
    int*   csr      = iws + 200001;              // [800000] -> 1000001
    int*   partials = iws + 1000016;             // [64]
    unsigned short* w1t  = usws + 2ull * 1000128; // [256*256]
    unsigned short* w2t  = usws + 2ull * 1032896; // [128*256]
    unsigned short* bufX = usws + 2ull * 1049280; // 12.8M ushorts: xb, then h2lin
    unsigned short* bufL16 = usws + 2ull * 7449280;  // h1lin bf16
    float*          bufLf  = fws + 7449280;          // h2 f32 (same region)
    unsigned short* bufH = usws + 2ull * 13849280;   // h1 bf16  (end word 20249280)

    hipMemsetAsync(deg, 0, NV * sizeof(int), stream);

    deg_kernel<<<(ETR + 255) / 256, 256, 0, stream>>>(tei, deg);
    partial_kernel<<<49, 1024, 0, stream>>>(deg, partials);
    ptr_kernel<<<49, 1024, 0, stream>>>(deg, partials, ptr, cursor, dinv);
    fill_kernel<<<(ETR + 255) / 256, 256, 0, stream>>>(tei, cursor, csr);

    cvt_x_kernel<<<(NV * 256 / 4 + 255) / 256, 256, 0, stream>>>(x, bufX, NV * 256 / 4);
    cvt_wt_kernel<<<(256 * 256 + 255) / 256, 256, 0, stream>>>(W1, w1t, 256, 256);
    cvt_wt_kernel<<<(128 * 256 + 255) / 256, 256, 0, stream>>>(W2, w2t, 256, 128);

    // layer 1
    mfma_gemm_kernel<256, 256, true><<<dim3(391, 2), 256, 0, stream>>>(bufX, w1t, bufL16, NV);
    gather_kernel<256, true, true><<<(NV * 64) / 256, 256, 0, stream>>>(ptr, csr, dinv, bufL16, b1, bufH);

    // layer 2 (h2lin overwrites bufX; h2 f32 overwrites bufL)
    mfma_gemm_kernel<128, 256, true><<<dim3(391, 1), 256, 0, stream>>>(bufH, w2t, bufX, NV);
    gather_kernel<128, false, false><<<(NV * 64) / 256, 256, 0, stream>>>(ptr, csr, dinv, bufX, b2, bufLf);

    // edge MLP head
    edge_mlp_tile_kernel<<<ETEST / 64, 256, 0, stream>>>(pos, neg, bufLf, Wl1, bl1, Wl2, bl2, out);
}

// Round 5
// 336.534 us; speedup vs baseline: 12.4984x; 1.1882x over previous
//
#include <hip/hip_runtime.h>
#include <math.h>

#define NV 50000
#define ETR 800000
#define EPOS 200000
#define ETEST 400000

typedef __attribute__((ext_vector_type(8))) short bf16x8;
typedef __attribute__((ext_vector_type(8))) unsigned short ushortx8;
typedef __attribute__((ext_vector_type(4))) float f32x4;

__device__ inline unsigned short f2b(float f) {
    union { float f; unsigned u; } v; v.f = f;
    unsigned r = v.u + 0x7fffu + ((v.u >> 16) & 1u);   // RNE
    return (unsigned short)(r >> 16);
}
__device__ inline float blo(unsigned q) { union { unsigned u; float f; } v; v.u = q << 16; return v.f; }
__device__ inline float bhi(unsigned q) { union { unsigned u; float f; } v; v.u = q & 0xffff0000u; return v.f; }
__device__ inline float b2f(unsigned short s) { union { unsigned u; float f; } v; v.u = ((unsigned)s) << 16; return v.f; }

__device__ inline ushortx8 bf16add8(ushortx8 a, ushortx8 b) {
    ushortx8 r;
    #pragma unroll
    for (int i = 0; i < 8; ++i)
        r[i] = f2b(b2f(a[i]) + b2f(b[i]));
    return r;
}

// ---------------- CSR build ----------------

__global__ void deg_kernel(const int* __restrict__ tei, int* __restrict__ deg) {
    int e = blockIdx.x * blockDim.x + threadIdx.x;
    if (e < ETR) atomicAdd(&deg[tei[ETR + e]], 1);
}

__global__ __launch_bounds__(1024) void partial_kernel(const int* __restrict__ deg,
                                                       int* __restrict__ partials) {
    int i = blockIdx.x * 1024 + threadIdx.x;
    int v = (i < NV) ? deg[i] : 0;
    #pragma unroll
    for (int off = 32; off > 0; off >>= 1) v += __shfl_xor(v, off);
    __shared__ int wsum[16];
    if ((threadIdx.x & 63) == 0) wsum[threadIdx.x >> 6] = v;
    __syncthreads();
    if (threadIdx.x == 0) {
        int s = 0;
        #pragma unroll
        for (int k = 0; k < 16; ++k) s += wsum[k];
        partials[blockIdx.x] = s;
    }
}

__global__ __launch_bounds__(1024) void ptr_kernel(
    const int* __restrict__ deg, const int* __restrict__ partials,
    int* __restrict__ ptr, int* __restrict__ cursor, float* __restrict__ dinv)
{
    int b = blockIdx.x, t = threadIdx.x;
    int i = b * 1024 + t;
    int d = (i < NV) ? deg[i] : 0;
    int lane = t & 63, w = t >> 6;
    int v = d;
    #pragma unroll
    for (int off = 1; off < 64; off <<= 1) {
        int u = __shfl_up(v, off);
        if (lane >= off) v += u;
    }
    __shared__ int wsum[16], woff[16];
    if (lane == 63) wsum[w] = v;
    __syncthreads();
    if (t == 0) {
        int s = 0;
        for (int k = 0; k < b; ++k) s += partials[k];
        for (int k = 0; k < 16; ++k) { woff[k] = s; s += wsum[k]; }
    }
    __syncthreads();
    int excl = woff[w] + v - d;
    if (i < NV) {
        ptr[i] = excl;
        cursor[i] = excl;
        dinv[i] = rsqrtf((float)d + 2.0f);   // SELF_LOOP_W = 2
        if (i == NV - 1) ptr[NV] = excl + d;
    }
}

__global__ void fill_kernel(const int* __restrict__ tei, int* __restrict__ cursor,
                            int* __restrict__ csr_row) {
    int e = blockIdx.x * blockDim.x + threadIdx.x;
    if (e < ETR) {
        int row = tei[e];
        int col = tei[ETR + e];
        int p = atomicAdd(&cursor[col], 1);
        csr_row[p] = row;
    }
}

// ---------------- converts ----------------

__global__ void cvt_x_kernel(const float* __restrict__ x, unsigned short* __restrict__ xb, int n4) {
    int i = blockIdx.x * blockDim.x + threadIdx.x;
    if (i < n4) {
        float4 v = *(const float4*)&x[i * 4];
        union { unsigned short u[4]; uint2 q; } o;
        o.u[0] = f2b(v.x); o.u[1] = f2b(v.y); o.u[2] = f2b(v.z); o.u[3] = f2b(v.w);
        *(uint2*)&xb[i * 4] = o.q;
    }
}

// Wt[n][k] = bf16(W[k][n])
__global__ void cvt_wt_kernel(const float* __restrict__ W, unsigned short* __restrict__ Wt,
                              int K, int N) {
    int idx = blockIdx.x * blockDim.x + threadIdx.x;
    if (idx < N * K) {
        int n = idx / K, k = idx - n * K;
        Wt[idx] = f2b(W[k * N + n]);
    }
}

// ---------------- bf16 MFMA GEMM: C[M][N] = A[M][K] @ Bt[N][K]^T ----------------
// 128x128 tile, 4 waves in 2x2, BK=64, 16x16x32 MFMA, XOR-swizzled LDS (T2).

template<int N, int K, bool OUTBF>
__global__ __launch_bounds__(256) void mfma_gemm_kernel(
    const unsigned short* __restrict__ A, const unsigned short* __restrict__ Bt,
    void* __restrict__ Cv, int M)
{
    constexpr int BK = 64;
    __shared__ unsigned short Asm[128][BK];
    __shared__ unsigned short Bsm[128][BK];
    int tid = threadIdx.x;
    int lane = tid & 63, wid = tid >> 6;
    int wr = wid >> 1, wc = wid & 1;
    int row0 = blockIdx.x * 128, col0 = blockIdx.y * 128;

    int sr = tid >> 3;
    int s8 = tid & 7;
    int sswz = s8 ^ (sr & 7);
    int fr = lane & 15;
    int g  = lane >> 4;

    f32x4 acc[4][4] = {};

    for (int k0 = 0; k0 < K; k0 += BK) {
        #pragma unroll
        for (int i = 0; i < 4; ++i) {
            int r = sr + i * 32;
            int gr = row0 + r;
            ushortx8 va = {0, 0, 0, 0, 0, 0, 0, 0};
            if (gr < M) va = *(const ushortx8*)&A[(size_t)gr * K + k0 + s8 * 8];
            *(ushortx8*)&Asm[r][sswz * 8] = va;
            ushortx8 vb = *(const ushortx8*)&Bt[(size_t)(col0 + r) * K + k0 + s8 * 8];
            *(ushortx8*)&Bsm[r][sswz * 8] = vb;
        }
        __syncthreads();
        #pragma unroll
        for (int kf = 0; kf < BK; kf += 32) {
            int sbase = kf >> 3;
            bf16x8 af[4], bfr[4];
            #pragma unroll
            for (int m = 0; m < 4; ++m) {
                int rr = wr * 64 + m * 16 + fr;
                af[m] = *(const bf16x8*)&Asm[rr][((sbase + g) ^ (fr & 7)) * 8];
            }
            #pragma unroll
            for (int n = 0; n < 4; ++n) {
                int rr = wc * 64 + n * 16 + fr;
                bfr[n] = *(const bf16x8*)&Bsm[rr][((sbase + g) ^ (fr & 7)) * 8];
            }
            #pragma unroll
            for (int m = 0; m < 4; ++m)
                #pragma unroll
                for (int n = 0; n < 4; ++n)
                    acc[m][n] = __builtin_amdgcn_mfma_f32_16x16x32_bf16(af[m], bfr[n], acc[m][n], 0, 0, 0);
        }
        __syncthreads();
    }

    // C/D layout: col = lane&15, row = (lane>>4)*4 + j
    #pragma unroll
    for (int m = 0; m < 4; ++m) {
        int rbase = row0 + wr * 64 + m * 16 + g * 4;
        #pragma unroll
        for (int j = 0; j < 4; ++j) {
            int r = rbase + j;
            if (r < M) {
                #pragma unroll
                for (int n = 0; n < 4; ++n) {
                    int c = col0 + wc * 64 + n * 16 + fr;
                    float v = acc[m][n][j];
                    if constexpr (OUTBF)
                        ((unsigned short*)Cv)[(size_t)r * N + c] = f2b(v);
                    else
                        ((float*)Cv)[(size_t)r * N + c] = v;
                }
            }
        }
    }
}

// ---------------- gather (bf16 in): hout[n] = relu?(sum_in + self + bias) ----------------

template<int F, bool RELU, bool OUTBF>
__global__ __launch_bounds__(256) void gather_kernel(
    const int* __restrict__ ptr, const int* __restrict__ csr,
    const float* __restrict__ dinv, const unsigned short* __restrict__ hlin,
    const float* __restrict__ bias, void* __restrict__ hout)
{
    constexpr int V = F / 64;
    int gid = blockIdx.x * blockDim.x + threadIdx.x;
    int node = gid >> 6, lane = gid & 63;
    if (node >= NV) return;
    float dc = dinv[node];
    int j0 = ptr[node], j1 = ptr[node + 1];
    float acc[V] = {};
    const unsigned short* hb = hlin + lane * V;

    int j = j0;
    for (; j + 1 < j1; j += 2) {
        int r0 = csr[j], r1 = csr[j + 1];
        float n0 = dinv[r0] * dc, n1 = dinv[r1] * dc;
        const unsigned short* p0 = hb + (size_t)r0 * F;
        const unsigned short* p1 = hb + (size_t)r1 * F;
        if constexpr (V == 4) {
            uint2 q0 = *(const uint2*)p0;
            uint2 q1 = *(const uint2*)p1;
            acc[0] += n0 * blo(q0.x) + n1 * blo(q1.x);
            acc[1] += n0 * bhi(q0.x) + n1 * bhi(q1.x);
            acc[2] += n0 * blo(q0.y) + n1 * blo(q1.y);
            acc[3] += n0 * bhi(q0.y) + n1 * bhi(q1.y);
        } else {
            unsigned q0 = *(const unsigned*)p0;
            unsigned q1 = *(const unsigned*)p1;
            acc[0] += n0 * blo(q0) + n1 * blo(q1);
            acc[1] += n0 * bhi(q0) + n1 * bhi(q1);
        }
    }
    if (j < j1) {
        int r0 = csr[j];
        float n0 = dinv[r0] * dc;
        const unsigned short* p0 = hb + (size_t)r0 * F;
        if constexpr (V == 4) {
            uint2 q0 = *(const uint2*)p0;
            acc[0] += n0 * blo(q0.x);
            acc[1] += n0 * bhi(q0.x);
            acc[2] += n0 * blo(q0.y);
            acc[3] += n0 * bhi(q0.y);
        } else {
            unsigned q0 = *(const unsigned*)p0;
            acc[0] += n0 * blo(q0);
            acc[1] += n0 * bhi(q0);
        }
    }

    const unsigned short* ps = hb + (size_t)node * F;
    float sw = 2.0f * dc * dc;
    float o[V];
    if constexpr (V == 4) {
        uint2 qs = *(const uint2*)ps;
        o[0] = acc[0] + sw * blo(qs.x) + bias[lane * 4 + 0];
        o[1] = acc[1] + sw * bhi(qs.x) + bias[lane * 4 + 1];
        o[2] = acc[2] + sw * blo(qs.y) + bias[lane * 4 + 2];
        o[3] = acc[3] + sw * bhi(qs.y) + bias[lane * 4 + 3];
    } else {
        unsigned qs = *(const unsigned*)ps;
        o[0] = acc[0] + sw * blo(qs) + bias[lane * 2 + 0];
        o[1] = acc[1] + sw * bhi(qs) + bias[lane * 2 + 1];
    }
    #pragma unroll
    for (int k = 0; k < V; ++k)
        if (RELU) o[k] = fmaxf(o[k], 0.0f);

    if constexpr (OUTBF) {
        unsigned short* op = (unsigned short*)hout + (size_t)node * F + lane * V;
        if constexpr (V == 4) {
            union { unsigned short u[4]; uint2 q; } pk;
            pk.u[0] = f2b(o[0]); pk.u[1] = f2b(o[1]); pk.u[2] = f2b(o[2]); pk.u[3] = f2b(o[3]);
            *(uint2*)op = pk.q;
        } else {
            union { unsigned short u[2]; unsigned q; } pk;
            pk.u[0] = f2b(o[0]); pk.u[1] = f2b(o[1]);
            *(unsigned*)op = pk.q;
        }
    } else {
        float* op = (float*)hout + (size_t)node * F + lane * V;
        if constexpr (V == 4)
            *(float4*)op = make_float4(o[0], o[1], o[2], o[3]);
        else
            *(float2*)op = make_float2(o[0], o[1]);
    }
}

// ---------------- edge MLP via MFMA ----------------
// 128 edges/block, 256 threads (4 waves). LDS: Es[128][128] bf16 (32KB, swizzled)
// + Ws[64][128] bf16 (16KB, swizzled) = 48KB -> 3 blocks/CU.
// Wave w: edges w*32..w*32+31 (2 m-tiles), all 64 hidden (4 n-tiles), K=128.

__global__ __launch_bounds__(256) void edge_mlp_mfma_kernel(
    const int* __restrict__ pos, const int* __restrict__ neg,
    const unsigned short* __restrict__ h2, const unsigned short* __restrict__ Wl1t,
    const float* __restrict__ bl1, const float* __restrict__ Wl2,
    const float* __restrict__ bl2, float* __restrict__ out)
{
    __shared__ unsigned short Es[128][128];
    __shared__ unsigned short Ws[64][128];
    int tid = threadIdx.x;
    int lane = tid & 63, w = tid >> 6;
    int fr = lane & 15, g = lane >> 4;
    int e0 = blockIdx.x * 128;

    // stage Wl1t [64][128] swizzled (1024 16B-chunks, coalesced)
    #pragma unroll
    for (int k = 0; k < 4; ++k) {
        int chunk = tid + k * 256;
        int row = chunk >> 4, c = chunk & 15;
        *(ushortx8*)&Ws[row][(c ^ (row & 7)) * 8] = *(const ushortx8*)&Wl1t[chunk * 8];
    }

    // stage E = h2[a] + h2[b], 2 threads per edge (64 feats each), swizzled
    int et = tid >> 1, hh = tid & 1;
    int eg = e0 + et;
    int a, b;
    if (eg < EPOS) { a = pos[eg]; b = pos[EPOS + eg]; }
    else { int i = eg - EPOS; a = neg[i]; b = neg[EPOS + i]; }
    const unsigned short* pa = h2 + (size_t)a * 128 + hh * 64;
    const unsigned short* pb = h2 + (size_t)b * 128 + hh * 64;
    #pragma unroll
    for (int c8 = 0; c8 < 8; ++c8) {
        ushortx8 va = *(const ushortx8*)&pa[c8 * 8];
        ushortx8 vb = *(const ushortx8*)&pb[c8 * 8];
        ushortx8 vs = bf16add8(va, vb);
        int c = hh * 8 + c8;
        *(ushortx8*)&Es[et][(c ^ (et & 7)) * 8] = vs;
    }
    __syncthreads();

    f32x4 acc[2][4] = {};
    #pragma unroll
    for (int ks = 0; ks < 4; ++ks) {
        int c = ks * 4 + g;
        bf16x8 af[2], bfr[4];
        #pragma unroll
        for (int m = 0; m < 2; ++m) {
            int r = w * 32 + m * 16 + fr;
            af[m] = *(const bf16x8*)&Es[r][(c ^ (r & 7)) * 8];
        }
        #pragma unroll
        for (int n = 0; n < 4; ++n) {
            int r = n * 16 + fr;
            bfr[n] = *(const bf16x8*)&Ws[r][(c ^ (r & 7)) * 8];
        }
        #pragma unroll
        for (int m = 0; m < 2; ++m)
            #pragma unroll
            for (int n = 0; n < 4; ++n)
                acc[m][n] = __builtin_amdgcn_mfma_f32_16x16x32_bf16(af[m], bfr[n], acc[m][n], 0, 0, 0);
    }

    // epilogue: per lane hidden n*16+fr, edges w*32+m*16+g*4+j
    float bl2v = bl2[0];
    float b1v[4], w2v[4];
    #pragma unroll
    for (int n = 0; n < 4; ++n) {
        b1v[n] = bl1[n * 16 + fr];
        w2v[n] = Wl2[n * 16 + fr];
    }
    #pragma unroll
    for (int m = 0; m < 2; ++m) {
        float p[4];
        #pragma unroll
        for (int j = 0; j < 4; ++j) {
            float s = 0.f;
            #pragma unroll
            for (int n = 0; n < 4; ++n)
                s += fmaxf(acc[m][n][j] + b1v[n], 0.0f) * w2v[n];
            p[j] = s;
        }
        #pragma unroll
        for (int off = 1; off < 16; off <<= 1) {
            #pragma unroll
            for (int j = 0; j < 4; ++j)
                p[j] += __shfl_xor(p[j], off);
        }
        int ebase = e0 + w * 32 + m * 16 + g * 4;
        #pragma unroll
        for (int j = 0; j < 4; ++j)
            if (fr == j)
                out[ebase + j] = 1.0f / (1.0f + expf(-(p[j] + bl2v)));
    }
}

// ---------------- launch ----------------

extern "C" void kernel_launch(void* const* d_in, const int* in_sizes, int n_in,
                              void* d_out, int out_size, void* d_ws, size_t ws_size,
                              hipStream_t stream) {
    const float* x   = (const float*)d_in[0];
    const int*   tei = (const int*)d_in[1];
    const int*   pos = (const int*)d_in[2];
    const int*   neg = (const int*)d_in[3];
    const float* W1  = (const float*)d_in[4];
    const float* b1  = (const float*)d_in[5];
    const float* W2  = (const float*)d_in[6];
    const float* b2  = (const float*)d_in[7];
    const float* Wl1 = (const float*)d_in[8];
    const float* bl1 = (const float*)d_in[9];
    const float* Wl2 = (const float*)d_in[10];
    const float* bl2 = (const float*)d_in[11];
    float* out = (float*)d_out;

    // workspace (word offsets):
    float* fws = (float*)d_ws;
    int*   iws = (int*)d_ws;
    unsigned short* usws = (unsigned short*)d_ws;
    float* dinv     = fws;                        // [50000]
    int*   deg      = iws + 50000;                // [50000]
    int*   ptr      = iws + 100000;               // [50001]
    int*   cursor   = iws + 150001;               // [50000]
    int*   csr      = iws + 200001;               // [800000] -> 1000001
    int*   partials = iws + 1000016;              // [64]
    unsigned short* w1t  = usws + 2ull * 1000128; // [256*256]
    unsigned short* w2t  = usws + 2ull * 1032896; // [128*256]
    unsigned short* bufX = usws + 2ull * 1049280; // 12.8M ushorts: xb, then h2lin
    unsigned short* bufL16 = usws + 2ull * 7449280;  // h1lin bf16, then h2 bf16
    unsigned short* bufH = usws + 2ull * 13849280;   // h1 bf16
    unsigned short* wl1t = usws + 2ull * 20249280;   // [64*128]

    hipMemsetAsync(deg, 0, NV * sizeof(int), stream);

    deg_kernel<<<(ETR + 255) / 256, 256, 0, stream>>>(tei, deg);
    partial_kernel<<<49, 1024, 0, stream>>>(deg, partials);
    ptr_kernel<<<49, 1024, 0, stream>>>(deg, partials, ptr, cursor, dinv);
    fill_kernel<<<(ETR + 255) / 256, 256, 0, stream>>>(tei, cursor, csr);

    cvt_x_kernel<<<(NV * 256 / 4 + 255) / 256, 256, 0, stream>>>(x, bufX, NV * 256 / 4);
    cvt_wt_kernel<<<(256 * 256 + 255) / 256, 256, 0, stream>>>(W1, w1t, 256, 256);
    cvt_wt_kernel<<<(128 * 256 + 255) / 256, 256, 0, stream>>>(W2, w2t, 256, 128);
    cvt_wt_kernel<<<(64 * 128 + 255) / 256, 256, 0, stream>>>(Wl1, wl1t, 128, 64);

    // layer 1
    mfma_gemm_kernel<256, 256, true><<<dim3(391, 2), 256, 0, stream>>>(bufX, w1t, bufL16, NV);
    gather_kernel<256, true, true><<<(NV * 64) / 256, 256, 0, stream>>>(ptr, csr, dinv, bufL16, b1, bufH);

    // layer 2 (h2lin overwrites bufX; h2 bf16 overwrites bufL16)
    mfma_gemm_kernel<128, 256, true><<<dim3(391, 1), 256, 0, stream>>>(bufH, w2t, bufX, NV);
    gather_kernel<128, false, true><<<(NV * 64) / 256, 256, 0, stream>>>(ptr, csr, dinv, bufX, b2, bufL16);

    // edge MLP head (MFMA)
    edge_mlp_mfma_kernel<<<ETEST / 128, 256, 0, stream>>>(pos, neg, bufL16, wl1t, bl1, Wl2, bl2, out);
}